// Round 9
// baseline (199.819 us; speedup 1.0000x reference)
//
#include <hip/hip_runtime.h>

#define BN_EPS 1e-5f
#define WW 56
#define HWSZ 3136      // 56*56
#define NB 32
#define CIN 240
#define MID 60
#define MIDG 20        // mid channels per group
#define COUT 240
#define COUTG 80

// ======== K1: grouped conv1x1 (240->60, G=3) + BN1 + ReLU -> t1 ========
// Thread = (position quad, ci-chunk). chunk = lane&3 covers 20 of the 80
// input channels; partial acc[20] (all out-channels of the group) is reduced
// across the 4 chunk-lanes with a shfl_xor butterfly. This gives kB's
// measured-good profile (20 loads : 1600 FMAs per thread) at 1176 blocks.
__global__ __launch_bounds__(256, 4) void k1_conv1_bn_relu(
        const float* __restrict__ x, const float* __restrict__ w1,
        const float* __restrict__ g1, const float* __restrict__ b1,
        const float* __restrict__ m1, const float* __restrict__ v1,
        float* __restrict__ t1) {
    __shared__ float wT[3 * 80 * MIDG];   // [g][ci][co], scale-folded; 19.2 KB
    __shared__ float sh1L[MID];
    const int tid = threadIdx.x;
    for (int i = tid; i < MID * 80; i += 256) {
        int co_glob = i / 80;             // w1 row
        int ci = i % 80;
        int gg = co_glob / MIDG, co = co_glob % MIDG;
        float s1v = g1[co_glob] * rsqrtf(v1[co_glob] + BN_EPS);
        wT[(gg * 80 + ci) * MIDG + co] = w1[i] * s1v;
    }
    if (tid < MID) {
        float s1v = g1[tid] * rsqrtf(v1[tid] + BN_EPS);
        sh1L[tid] = b1[tid] - m1[tid] * s1v;
    }
    __syncthreads();

    const int item  = blockIdx.x * 256 + tid;   // < 32*3*784*4 = 301056
    const int chunk = item & 3;                 // lane&3: which 20 input chans
    const int pg    = item >> 2;                // position index < 75264
    const int p4    = pg % 784;
    const int bg    = pg / 784;
    const int b = bg / 3, g = bg % 3;
    const int pos = p4 * 4;

    const float* xp = x + ((size_t)(b * CIN + g * 80 + chunk * 20)) * HWSZ + pos;
    const float* wbase = wT + (g * 80 + chunk * 20) * MIDG;

    float4 acc[MIDG];
#pragma unroll
    for (int j = 0; j < MIDG; j++) acc[j] = make_float4(0.f, 0.f, 0.f, 0.f);

#pragma unroll 4
    for (int ci = 0; ci < 20; ci++) {
        float4 xv = *(const float4*)(xp + (size_t)ci * HWSZ);
        const float4* wrow = (const float4*)(wbase + ci * MIDG);
#pragma unroll
        for (int k4 = 0; k4 < 5; k4++) {
            float4 wv = wrow[k4];
            acc[k4 * 4 + 0].x += wv.x * xv.x; acc[k4 * 4 + 0].y += wv.x * xv.y;
            acc[k4 * 4 + 0].z += wv.x * xv.z; acc[k4 * 4 + 0].w += wv.x * xv.w;
            acc[k4 * 4 + 1].x += wv.y * xv.x; acc[k4 * 4 + 1].y += wv.y * xv.y;
            acc[k4 * 4 + 1].z += wv.y * xv.z; acc[k4 * 4 + 1].w += wv.y * xv.w;
            acc[k4 * 4 + 2].x += wv.z * xv.x; acc[k4 * 4 + 2].y += wv.z * xv.y;
            acc[k4 * 4 + 2].z += wv.z * xv.z; acc[k4 * 4 + 2].w += wv.z * xv.w;
            acc[k4 * 4 + 3].x += wv.w * xv.x; acc[k4 * 4 + 3].y += wv.w * xv.y;
            acc[k4 * 4 + 3].z += wv.w * xv.z; acc[k4 * 4 + 3].w += wv.w * xv.w;
        }
    }

    // ---- butterfly-reduce partial sums across the 4 chunk-lanes ----
#pragma unroll
    for (int j = 0; j < MIDG; j++) {
        acc[j].x += __shfl_xor(acc[j].x, 1); acc[j].y += __shfl_xor(acc[j].y, 1);
        acc[j].z += __shfl_xor(acc[j].z, 1); acc[j].w += __shfl_xor(acc[j].w, 1);
        acc[j].x += __shfl_xor(acc[j].x, 2); acc[j].y += __shfl_xor(acc[j].y, 2);
        acc[j].z += __shfl_xor(acc[j].z, 2); acc[j].w += __shfl_xor(acc[j].w, 2);
    }

    // ---- each chunk-lane stores 5 of the 20 out-channels (static indexing) ----
#pragma unroll
    for (int j = 0; j < MIDG; j++) {
        if (j / 5 == chunk) {               // j/5 compile-time; exec-masked store
            int ch = g * MIDG + j;
            float sf = sh1L[ch];
            float4 o;
            o.x = fmaxf(acc[j].x + sf, 0.f);
            o.y = fmaxf(acc[j].y + sf, 0.f);
            o.z = fmaxf(acc[j].z + sf, 0.f);
            o.w = fmaxf(acc[j].w + sf, 0.f);
            *(float4*)(t1 + ((size_t)(b * MID + ch)) * HWSZ + pos) = o;
        }
    }
}

// ======== K2: depthwise 3x3 (pad 1) + BN2 -> t2, written channel-shuffled ====
__global__ __launch_bounds__(256) void k2_dw_bn_shuffle(
        const float* __restrict__ t1, const float* __restrict__ w2,
        const float* __restrict__ g2, const float* __restrict__ b2,
        const float* __restrict__ m2, const float* __restrict__ v2,
        float* __restrict__ t2) {
    const int item = blockIdx.x * 256 + threadIdx.x;   // < 32*60*784 = 1505280
    const unsigned bc = (unsigned)item / 784u;
    const unsigned p4 = (unsigned)item % 784u;
    const unsigned c = bc % (unsigned)MID;
    const unsigned b = bc / (unsigned)MID;
    const int pos = (int)p4 * 4;
    const int h = pos / WW;
    const int w = pos % WW;                            // w in {0,4,...,52}

    const float inv = g2[c] * rsqrtf(v2[c] + BN_EPS);
    const float sf  = b2[c] - m2[c] * inv;
    const float* base = t1 + (size_t)bc * HWSZ;
    float kf[9];
#pragma unroll
    for (int i = 0; i < 9; i++) kf[i] = w2[c * 9 + i] * inv;

    float acc0 = 0.f, acc1 = 0.f, acc2 = 0.f, acc3 = 0.f;
#pragma unroll
    for (int dy = -1; dy <= 1; dy++) {
        int r = h + dy;
        if (r < 0 || r >= 56) continue;
        const float* row = base + r * WW + w;
        float4 mid4 = *(const float4*)row;
        float v0 = (w > 0) ? row[-1] : 0.f;
        float v5 = (w + 4 < WW) ? row[4] : 0.f;
        const float k0 = kf[(dy + 1) * 3 + 0];
        const float k1 = kf[(dy + 1) * 3 + 1];
        const float k2 = kf[(dy + 1) * 3 + 2];
        acc0 += k0 * v0     + k1 * mid4.x + k2 * mid4.y;
        acc1 += k0 * mid4.x + k1 * mid4.y + k2 * mid4.z;
        acc2 += k0 * mid4.y + k1 * mid4.z + k2 * mid4.w;
        acc3 += k0 * mid4.z + k1 * mid4.w + k2 * v5;
    }

    float4 o;
    o.x = acc0 + sf; o.y = acc1 + sf; o.z = acc2 + sf; o.w = acc3 + sf;
    const unsigned jj = (c % 20u) * 3u + c / 20u;      // shuffled channel index
    *(float4*)(t2 + ((size_t)(b * MID + jj)) * HWSZ + pos) = o;
}

// ======== K3: grouped conv1x1 (60->240, inputs pre-shuffled) + BN3 + ReLU
//          + residual add. One thread: one float4 of positions, 20 out-channels
//          (q = item&3 -> lanes 0-3 share t2 loads, dedup'd in the coalescer).
__global__ __launch_bounds__(256) void kB_conv3_res(
        const float* __restrict__ t2, const float* __restrict__ w3,
        const float* __restrict__ g3, const float* __restrict__ b3,
        const float* __restrict__ m3, const float* __restrict__ v3,
        const float* __restrict__ x, float* __restrict__ out) {
    __shared__ float wT[3 * MIDG * COUTG];  // [g][ci][cg] : 4800 floats
    __shared__ float s3[COUT], sh3[COUT];
    const int tid = threadIdx.x;
    for (int i = tid; i < 3 * MIDG * COUTG; i += 256) {
        int co_glob = i / MIDG;     // row of w3
        int ci = i % MIDG;
        int gg = co_glob / COUTG;
        int cg = co_glob % COUTG;
        wT[(gg * MIDG + ci) * COUTG + cg] = w3[i];
    }
    if (tid < COUT) {
        float inv = g3[tid] * rsqrtf(v3[tid] + BN_EPS);
        s3[tid] = inv;
        sh3[tid] = b3[tid] - m3[tid] * inv;
    }
    __syncthreads();

    const int item = blockIdx.x * 256 + tid;  // < 301056
    const unsigned q  = (unsigned)item & 3u;  // out-channel quarter
    const unsigned pg = (unsigned)item >> 2;
    const unsigned p4 = pg % 784u;
    const unsigned bg = pg / 784u;
    const unsigned b = bg / 3u, g = bg % 3u;
    const int pos = (int)p4 * 4;

    float4 acc[MIDG];
#pragma unroll
    for (int c = 0; c < MIDG; c++) acc[c] = make_float4(0.f, 0.f, 0.f, 0.f);

    const float4* wl4 = (const float4*)wT;
#pragma unroll 4
    for (int ci = 0; ci < MIDG; ci++) {
        int csh = (int)g * MIDG + ci;          // t2 pre-shuffled: read linearly
        float4 xv = *(const float4*)(t2 + ((size_t)(b * MID + csh)) * HWSZ + pos);
        int wbase = (csh * COUTG + q * MIDG) / 4;  // float4 index
#pragma unroll
        for (int k4 = 0; k4 < 5; k4++) {
            float4 wv = wl4[wbase + k4];
            acc[k4 * 4 + 0].x += wv.x * xv.x; acc[k4 * 4 + 0].y += wv.x * xv.y;
            acc[k4 * 4 + 0].z += wv.x * xv.z; acc[k4 * 4 + 0].w += wv.x * xv.w;
            acc[k4 * 4 + 1].x += wv.y * xv.x; acc[k4 * 4 + 1].y += wv.y * xv.y;
            acc[k4 * 4 + 1].z += wv.y * xv.z; acc[k4 * 4 + 1].w += wv.y * xv.w;
            acc[k4 * 4 + 2].x += wv.z * xv.x; acc[k4 * 4 + 2].y += wv.z * xv.y;
            acc[k4 * 4 + 2].z += wv.z * xv.z; acc[k4 * 4 + 2].w += wv.z * xv.w;
            acc[k4 * 4 + 3].x += wv.w * xv.x; acc[k4 * 4 + 3].y += wv.w * xv.y;
            acc[k4 * 4 + 3].z += wv.w * xv.z; acc[k4 * 4 + 3].w += wv.w * xv.w;
        }
    }

#pragma unroll
    for (int co = 0; co < MIDG; co++) {
        int cg = (int)g * COUTG + (int)q * MIDG + co;
        float sc = s3[cg], sf = sh3[cg];
        float4 xr = *(const float4*)(x + ((size_t)(b * CIN + cg)) * HWSZ + pos);
        float4 o;
        o.x = fmaxf(acc[co].x * sc + sf, 0.f) + xr.x;
        o.y = fmaxf(acc[co].y * sc + sf, 0.f) + xr.y;
        o.z = fmaxf(acc[co].z * sc + sf, 0.f) + xr.z;
        o.w = fmaxf(acc[co].w * sc + sf, 0.f) + xr.w;
        *(float4*)(out + ((size_t)(b * CIN + cg)) * HWSZ + pos) = o;
    }
}

extern "C" void kernel_launch(void* const* d_in, const int* in_sizes, int n_in,
                              void* d_out, int out_size, void* d_ws, size_t ws_size,
                              hipStream_t stream) {
    const float* x  = (const float*)d_in[0];
    const float* w1 = (const float*)d_in[1];
    const float* g1 = (const float*)d_in[2];
    const float* b1 = (const float*)d_in[3];
    const float* m1 = (const float*)d_in[4];
    const float* v1 = (const float*)d_in[5];
    const float* w2 = (const float*)d_in[6];
    const float* g2 = (const float*)d_in[7];
    const float* b2 = (const float*)d_in[8];
    const float* m2 = (const float*)d_in[9];
    const float* v2 = (const float*)d_in[10];
    const float* w3 = (const float*)d_in[11];
    const float* g3 = (const float*)d_in[12];
    const float* b3 = (const float*)d_in[13];
    const float* m3 = (const float*)d_in[14];
    const float* v3 = (const float*)d_in[15];
    float* out = (float*)d_out;

    float* t1 = (float*)d_ws;                          // 24 MB
    float* t2 = t1 + (size_t)NB * MID * HWSZ;          // 24 MB (shuffled)

    // K1: 301056 threads / 256 = 1176 blocks
    k1_conv1_bn_relu<<<1176, 256, 0, stream>>>(x, w1, g1, b1, m1, v1, t1);
    // K2: 1505280 / 256 = 5880 blocks
    k2_dw_bn_shuffle<<<5880, 256, 0, stream>>>(t1, w2, g2, b2, m2, v2, t2);
    // K3: 301056 / 256 = 1176 blocks
    kB_conv3_res<<<1176, 256, 0, stream>>>(t2, w3, g3, b3, m3, v3, x, out);
}

// Round 10
// 105.534 us; speedup vs baseline: 1.8934x; 1.8934x over previous
//
#include <hip/hip_runtime.h>
#include <stdint.h>

#define BN_EPS 1e-5f
#define WW 56
#define HWSZ 3136      // 56*56
#define NB 32
#define CIN 240
#define MID 60
#define MIDG 20        // mid channels per group
#define COUT 240
#define COUTG 80
#define TROWS 8        // rows per k1 tile (56 = 7*8)
#define NT 7
#define CHUNK_CI 8     // input channels per staged chunk
#define NCHUNK 10      // 80 / 8
#define CHUNK_FLOATS (CHUNK_CI * TROWS * WW)   // 3584 floats = 14336 B
#define ISSUES 14      // 14336 / 1024 B per wave-issue

typedef const __attribute__((address_space(1))) void* gas_t;
typedef __attribute__((address_space(3))) void* las_t;

__device__ __forceinline__ void gload_lds16(const float* g, float* l) {
    __builtin_amdgcn_global_load_lds((gas_t)g, (las_t)l, 16, 0, 0);
}

// ======== K1: grouped conv1x1 (240->60) + BN1 + ReLU -> t1 ========
// Async 2-phase: global_load_lds stages chunk c+1 (14 wave-issues, no VGPRs)
// while computing chunk c from LDS. Double-buffered; one barrier per chunk.
// Block = (b, g, 8-row tile): 672 blocks, 256 threads, LDS ~35.5 KB.
__global__ __launch_bounds__(256, 4) void k1_conv1_async(
        const float* __restrict__ x, const float* __restrict__ w1,
        const float* __restrict__ g1, const float* __restrict__ b1,
        const float* __restrict__ m1, const float* __restrict__ v1,
        float* __restrict__ t1) {
    __shared__ float xbuf[2][CHUNK_FLOATS];   // 2 x 14,336 B
    __shared__ float w1s[MIDG * 80];          // scale-folded [cl][ciG], 6.4 KB
    __shared__ float shA[MIDG];

    const int tid = threadIdx.x;
    const int bid = blockIdx.x;               // < 672
    const int t  = bid % NT;
    const int gb = bid / NT;
    const int g  = gb % 3;
    const int b  = gb / 3;
    const int h0 = t * TROWS;

    // stage scale-folded weights + shifts (drained by first barrier)
    for (int i = tid; i < MIDG * 80; i += 256) {
        int cl = i / 80;
        int chg = g * MIDG + cl;
        w1s[i] = w1[chg * 80 + (i % 80)] * (g1[chg] * rsqrtf(v1[chg] + BN_EPS));
    }
    if (tid < MIDG) {
        int chg = g * MIDG + tid;
        float s1v = g1[chg] * rsqrtf(v1[chg] + BN_EPS);
        shA[tid] = b1[chg] - m1[chg] * s1v;
    }

    const int lane = tid & 63;
    const int wv   = tid >> 6;
    const float* xg = x + ((size_t)(b * CIN + g * 80)) * HWSZ;

    // per-issue global float offsets (constant across chunks; ci*HWSZ folded in)
    int base_off[4];
#pragma unroll
    for (int k = 0; k < 4; k++) {
        int j = wv + k * 4;
        int off_f = j * 256 + lane * 4;              // linear float off in chunk
        int ci = off_f / (TROWS * WW);               // /448
        int rem = off_f - ci * (TROWS * WW);
        base_off[k] = ci * HWSZ + h0 * WW + rem;
        if (j >= ISSUES) base_off[k] = -1;
    }

    // prologue: stage chunk 0 into xbuf[0]
#pragma unroll
    for (int k = 0; k < 4; k++) {
        int j = wv + k * 4;
        if (j < ISSUES) gload_lds16(xg + base_off[k], &xbuf[0][j * 256]);
    }
    __syncthreads();   // drains weight stores + chunk-0 DMA

    const int half = tid >> 7;        // 0/1 -> out-channels half*10..+9
    const int slot = tid & 127;       // position quad within 8x14
    const bool act = slot < 112;
    const int r  = slot / 14, c4 = slot % 14;

    float4 acc[10];
#pragma unroll
    for (int c = 0; c < 10; c++) acc[c] = make_float4(0.f, 0.f, 0.f, 0.f);

    for (int c = 0; c < NCHUNK; ++c) {
        const int cur = c & 1;
        // ---- issue next chunk's DMA before computing (overlap) ----
        if (c + 1 < NCHUNK) {
            const float* gsrc = xg + (size_t)(c + 1) * CHUNK_CI * HWSZ;
#pragma unroll
            for (int k = 0; k < 4; k++) {
                int j = wv + k * 4;
                if (j < ISSUES) gload_lds16(gsrc + base_off[k], &xbuf[cur ^ 1][j * 256]);
            }
        }
        // ---- compute chunk c from LDS ----
        if (act) {
            float4 xv[CHUNK_CI];
#pragma unroll
            for (int ci = 0; ci < CHUNK_CI; ci++)
                xv[ci] = *(const float4*)&xbuf[cur][ci * (TROWS * WW) + slot * 4];
#pragma unroll
            for (int cc = 0; cc < 10; cc++) {
                const float* wp = &w1s[(half * 10 + cc) * 80 + c * CHUNK_CI];
                float4 wa = *(const float4*)(wp);      // wave-uniform broadcast
                float4 wb = *(const float4*)(wp + 4);
                acc[cc].x += wa.x * xv[0].x + wa.y * xv[1].x + wa.z * xv[2].x + wa.w * xv[3].x
                           + wb.x * xv[4].x + wb.y * xv[5].x + wb.z * xv[6].x + wb.w * xv[7].x;
                acc[cc].y += wa.x * xv[0].y + wa.y * xv[1].y + wa.z * xv[2].y + wa.w * xv[3].y
                           + wb.x * xv[4].y + wb.y * xv[5].y + wb.z * xv[6].y + wb.w * xv[7].y;
                acc[cc].z += wa.x * xv[0].z + wa.y * xv[1].z + wa.z * xv[2].z + wa.w * xv[3].z
                           + wb.x * xv[4].z + wb.y * xv[5].z + wb.z * xv[6].z + wb.w * xv[7].z;
                acc[cc].w += wa.x * xv[0].w + wa.y * xv[1].w + wa.z * xv[2].w + wa.w * xv[3].w
                           + wb.x * xv[4].w + wb.y * xv[5].w + wb.z * xv[6].w + wb.w * xv[7].w;
            }
        }
        __syncthreads();   // drains this iter's DMA; frees buf for next overwrite
    }

    // ---- BN1 shift + ReLU -> t1 ----
    if (act) {
#pragma unroll
        for (int cc = 0; cc < 10; cc++) {
            int cl = half * 10 + cc;
            int ch = g * MIDG + cl;
            float sf = shA[cl];
            float4 o;
            o.x = fmaxf(acc[cc].x + sf, 0.f);
            o.y = fmaxf(acc[cc].y + sf, 0.f);
            o.z = fmaxf(acc[cc].z + sf, 0.f);
            o.w = fmaxf(acc[cc].w + sf, 0.f);
            *(float4*)(t1 + ((size_t)(b * MID + ch)) * HWSZ + (h0 + r) * WW + c4 * 4) = o;
        }
    }
}

// ======== K2: depthwise 3x3 (pad 1) + BN2 -> t2, written channel-shuffled ====
__global__ __launch_bounds__(256) void k2_dw_bn_shuffle(
        const float* __restrict__ t1, const float* __restrict__ w2,
        const float* __restrict__ g2, const float* __restrict__ b2,
        const float* __restrict__ m2, const float* __restrict__ v2,
        float* __restrict__ t2) {
    const int item = blockIdx.x * 256 + threadIdx.x;   // < 1505280
    const unsigned bc = (unsigned)item / 784u;
    const unsigned p4 = (unsigned)item % 784u;
    const unsigned c = bc % (unsigned)MID;
    const unsigned b = bc / (unsigned)MID;
    const int pos = (int)p4 * 4;
    const int h = pos / WW;
    const int w = pos % WW;

    const float inv = g2[c] * rsqrtf(v2[c] + BN_EPS);
    const float sf  = b2[c] - m2[c] * inv;
    const float* base = t1 + (size_t)bc * HWSZ;
    float kf[9];
#pragma unroll
    for (int i = 0; i < 9; i++) kf[i] = w2[c * 9 + i] * inv;

    float acc0 = 0.f, acc1 = 0.f, acc2 = 0.f, acc3 = 0.f;
#pragma unroll
    for (int dy = -1; dy <= 1; dy++) {
        int rr = h + dy;
        if (rr < 0 || rr >= 56) continue;
        const float* row = base + rr * WW + w;
        float4 mid4 = *(const float4*)row;
        float v0 = (w > 0) ? row[-1] : 0.f;
        float v5 = (w + 4 < WW) ? row[4] : 0.f;
        const float k0 = kf[(dy + 1) * 3 + 0];
        const float k1 = kf[(dy + 1) * 3 + 1];
        const float k2 = kf[(dy + 1) * 3 + 2];
        acc0 += k0 * v0     + k1 * mid4.x + k2 * mid4.y;
        acc1 += k0 * mid4.x + k1 * mid4.y + k2 * mid4.z;
        acc2 += k0 * mid4.y + k1 * mid4.z + k2 * mid4.w;
        acc3 += k0 * mid4.z + k1 * mid4.w + k2 * v5;
    }

    float4 o;
    o.x = acc0 + sf; o.y = acc1 + sf; o.z = acc2 + sf; o.w = acc3 + sf;
    const unsigned jj = (c % 20u) * 3u + c / 20u;      // shuffled channel index
    *(float4*)(t2 + ((size_t)(b * MID + jj)) * HWSZ + pos) = o;
}

// ======== K3: grouped conv1x1 (60->240, inputs pre-shuffled) + BN3 + ReLU
//          + residual add ========
__global__ __launch_bounds__(256) void kB_conv3_res(
        const float* __restrict__ t2, const float* __restrict__ w3,
        const float* __restrict__ g3, const float* __restrict__ b3,
        const float* __restrict__ m3, const float* __restrict__ v3,
        const float* __restrict__ x, float* __restrict__ out) {
    __shared__ float wT[3 * MIDG * COUTG];  // [g][ci][cg] : 4800 floats
    __shared__ float s3[COUT], sh3[COUT];
    const int tid = threadIdx.x;
    for (int i = tid; i < 3 * MIDG * COUTG; i += 256) {
        int co_glob = i / MIDG;
        int ci = i % MIDG;
        int gg = co_glob / COUTG;
        int cg = co_glob % COUTG;
        wT[(gg * MIDG + ci) * COUTG + cg] = w3[i];
    }
    if (tid < COUT) {
        float inv = g3[tid] * rsqrtf(v3[tid] + BN_EPS);
        s3[tid] = inv;
        sh3[tid] = b3[tid] - m3[tid] * inv;
    }
    __syncthreads();

    const int item = blockIdx.x * 256 + tid;  // < 301056
    const unsigned q  = (unsigned)item & 3u;
    const unsigned pg = (unsigned)item >> 2;
    const unsigned p4 = pg % 784u;
    const unsigned bg = pg / 784u;
    const unsigned b = bg / 3u, g = bg % 3u;
    const int pos = (int)p4 * 4;

    float4 acc[MIDG];
#pragma unroll
    for (int c = 0; c < MIDG; c++) acc[c] = make_float4(0.f, 0.f, 0.f, 0.f);

    const float4* wl4 = (const float4*)wT;
#pragma unroll 4
    for (int ci = 0; ci < MIDG; ci++) {
        int csh = (int)g * MIDG + ci;
        float4 xv = *(const float4*)(t2 + ((size_t)(b * MID + csh)) * HWSZ + pos);
        int wbase = (csh * COUTG + q * MIDG) / 4;
#pragma unroll
        for (int k4 = 0; k4 < 5; k4++) {
            float4 wv = wl4[wbase + k4];
            acc[k4 * 4 + 0].x += wv.x * xv.x; acc[k4 * 4 + 0].y += wv.x * xv.y;
            acc[k4 * 4 + 0].z += wv.x * xv.z; acc[k4 * 4 + 0].w += wv.x * xv.w;
            acc[k4 * 4 + 1].x += wv.y * xv.x; acc[k4 * 4 + 1].y += wv.y * xv.y;
            acc[k4 * 4 + 1].z += wv.y * xv.z; acc[k4 * 4 + 1].w += wv.y * xv.w;
            acc[k4 * 4 + 2].x += wv.z * xv.x; acc[k4 * 4 + 2].y += wv.z * xv.y;
            acc[k4 * 4 + 2].z += wv.z * xv.z; acc[k4 * 4 + 2].w += wv.z * xv.w;
            acc[k4 * 4 + 3].x += wv.w * xv.x; acc[k4 * 4 + 3].y += wv.w * xv.y;
            acc[k4 * 4 + 3].z += wv.w * xv.z; acc[k4 * 4 + 3].w += wv.w * xv.w;
        }
    }

#pragma unroll
    for (int co = 0; co < MIDG; co++) {
        int cg = (int)g * COUTG + (int)q * MIDG + co;
        float sc = s3[cg], sf = sh3[cg];
        float4 xr = *(const float4*)(x + ((size_t)(b * CIN + cg)) * HWSZ + pos);
        float4 o;
        o.x = fmaxf(acc[co].x * sc + sf, 0.f) + xr.x;
        o.y = fmaxf(acc[co].y * sc + sf, 0.f) + xr.y;
        o.z = fmaxf(acc[co].z * sc + sf, 0.f) + xr.z;
        o.w = fmaxf(acc[co].w * sc + sf, 0.f) + xr.w;
        *(float4*)(out + ((size_t)(b * CIN + cg)) * HWSZ + pos) = o;
    }
}

extern "C" void kernel_launch(void* const* d_in, const int* in_sizes, int n_in,
                              void* d_out, int out_size, void* d_ws, size_t ws_size,
                              hipStream_t stream) {
    const float* x  = (const float*)d_in[0];
    const float* w1 = (const float*)d_in[1];
    const float* g1 = (const float*)d_in[2];
    const float* b1 = (const float*)d_in[3];
    const float* m1 = (const float*)d_in[4];
    const float* v1 = (const float*)d_in[5];
    const float* w2 = (const float*)d_in[6];
    const float* g2 = (const float*)d_in[7];
    const float* b2 = (const float*)d_in[8];
    const float* m2 = (const float*)d_in[9];
    const float* v2 = (const float*)d_in[10];
    const float* w3 = (const float*)d_in[11];
    const float* g3 = (const float*)d_in[12];
    const float* b3 = (const float*)d_in[13];
    const float* m3 = (const float*)d_in[14];
    const float* v3 = (const float*)d_in[15];
    float* out = (float*)d_out;

    float* t1 = (float*)d_ws;                          // 24 MB
    float* t2 = t1 + (size_t)NB * MID * HWSZ;          // 24 MB (shuffled)

    // K1: 32 b * 3 g * 7 tiles = 672 blocks
    k1_conv1_async<<<672, 256, 0, stream>>>(x, w1, g1, b1, m1, v1, t1);
    // K2: 1505280 / 256 = 5880 blocks
    k2_dw_bn_shuffle<<<5880, 256, 0, stream>>>(t1, w2, g2, b2, m2, v2, t2);
    // K3: 301056 / 256 = 1176 blocks
    kB_conv3_res<<<1176, 256, 0, stream>>>(t2, w3, g3, b3, m3, v3, x, out);
}